// Round 17
// baseline (222.677 us; speedup 1.0000x reference)
//
#include <hip/hip_runtime.h>

#define Hh 32
#define Ss 2048
#define Ee 512
#define Dd 32
#define LOG2E 1.4426950408889634f
#define KV_SPLIT 8
#define KV_LEN (Ss / KV_SPLIT)   // 256 keys per wave

typedef __attribute__((ext_vector_type(4))) float f32x4;
typedef __attribute__((ext_vector_type(4))) int i32x4;
typedef __attribute__((ext_vector_type(8))) __bf16 bf16x8;
typedef __attribute__((ext_vector_type(8))) unsigned short ushort8;
typedef __attribute__((ext_vector_type(4))) unsigned short ushort4v;

// float -> bf16 round-to-nearest-even, as raw ushort
__device__ inline unsigned short f2bf(float f) {
  union { float f; unsigned u; } x; x.f = f;
  unsigned r = x.u + 0x7fffu + ((x.u >> 16) & 1u);
  return (unsigned short)(r >> 16);
}

// ---------------- Prep: pack mask int32 -> bits, convert Wq|Wk|Wv -> bf16
__global__ __launch_bounds__(256) void prep_kernel(
    const int* __restrict__ mask, unsigned int* __restrict__ bits,
    const float* __restrict__ Wq, const float* __restrict__ Wk,
    const float* __restrict__ Wv, unsigned short* __restrict__ Wb) {
  int b = (int)blockIdx.x, t = (int)threadIdx.x;
  if (b < 512) {
    int w = b * 256 + t;  // word index 0..S*S/32-1
    const i32x4* p = (const i32x4*)(mask + (size_t)w * 32);
    unsigned int bs = 0;
    #pragma unroll
    for (int i = 0; i < 8; ++i) {
      i32x4 v = __builtin_nontemporal_load(&p[i]);   // stream-once: bypass L3
      bs |= (v.x ? 1u : 0u) << (4 * i + 0);
      bs |= (v.y ? 1u : 0u) << (4 * i + 1);
      bs |= (v.z ? 1u : 0u) << (4 * i + 2);
      bs |= (v.w ? 1u : 0u) << (4 * i + 3);
    }
    bits[w] = bs;
  } else {
    int i = (b - 512) * 1024 + t * 4;  // 48 blocks cover 3*32*512 = 49152 elems
    const float* src = (i < 16384) ? (Wq + i)
                     : (i < 32768) ? (Wk + (i - 16384)) : (Wv + (i - 32768));
    f32x4 v = *(const f32x4*)src;
    ushort4v o = { f2bf(v.x), f2bf(v.y), f2bf(v.z), f2bf(v.w) };
    *(ushort4v*)(Wb + i) = o;
  }
}

// ---------------- Merged projections, BARRIER-FREE per-wave pipeline with
// NONTEMPORAL input loads. Identical to the round-16 passing kernel
// (V in tile-interleaved layout Vt2[h][s/32][d][kk]).
__global__ __launch_bounds__(256) void proj_kernel(
    const float* __restrict__ Xq, const float* __restrict__ Xk,
    const float* __restrict__ Xv, const unsigned short* __restrict__ Wb,
    const float* __restrict__ bq, const float* __restrict__ bk,
    const float* __restrict__ bv, const float* __restrict__ inv_scale,
    unsigned short* __restrict__ Qb, unsigned short* __restrict__ Kb,
    unsigned short* __restrict__ Vtb) {
  __shared__ unsigned short sb[4][2][16 * 64];   // [wave][buf][16 rows x 64 bf16]

  int blk  = (int)blockIdx.x;
  int seg  = blk >> 10;
  int tid  = (int)threadIdx.x;
  int wv   = tid >> 6, lane = tid & 63;
  int g = lane >> 4, li = lane & 15;
  int lr = lane >> 4;      // row-within-quad for loads (0..3)
  int lc = lane & 15;      // col group (4 floats = 16 B)
  int R0 = (blk & 1023) * 64;        // block row base within segment
  int h  = R0 >> 11;
  int s0 = R0 & 2047;

  const float* X    = (seg == 0) ? Xq : (seg == 1) ? Xk : Xv;
  const float* bias = (seg == 0) ? bq : (seg == 1) ? bk : bv;
  const unsigned short* W = Wb + seg * (Dd * Ee);
  const float* xw = X + (size_t)(R0 + wv * 16) * Ee;   // wave's 16 rows

  unsigned short (*mybuf)[16 * 64] = sb[wv];

  auto ld = [&](int c, int i) -> f32x4 {
    return __builtin_nontemporal_load(
        (const f32x4*)(xw + (size_t)(4 * i + lr) * Ee + c * 64 + lc * 4));
  };
  auto wr = [&](int buf, int i, f32x4 v) {
    int r = 4 * i + lr;
    int byteoff = (lc * 8) ^ ((r & 7) << 4);
    ushort4v u = { f2bf(v.x), f2bf(v.y), f2bf(v.z), f2bf(v.w) };
    *(ushort4v*)&mybuf[buf][r * 64 + (byteoff >> 1)] = u;
  };
  auto rd = [&](int buf, int half) -> bf16x8 {
    int byteoff = (half * 64 + g * 16) ^ ((li & 7) << 4);
    return __builtin_bit_cast(bf16x8,
        *(const ushort8*)&mybuf[buf][li * 64 + (byteoff >> 1)]);
  };

  f32x4 acc0 = {0.f, 0.f, 0.f, 0.f};
  f32x4 acc1 = {0.f, 0.f, 0.f, 0.f};

  f32x4 A0 = ld(0, 0), A1 = ld(0, 1), A2 = ld(0, 2), A3 = ld(0, 3);
  f32x4 B0 = ld(1, 0), B1 = ld(1, 1), B2 = ld(1, 2), B3 = ld(1, 3);

  #pragma unroll
  for (int c = 0; c < 8; c += 2) {
    wr(0, 0, A0); wr(0, 1, A1); wr(0, 2, A2); wr(0, 3, A3);
    {
      int cn = (c + 2 < 8) ? (c + 2) : 6;   // clamped redundant reload
      A0 = ld(cn, 0); A1 = ld(cn, 1); A2 = ld(cn, 2); A3 = ld(cn, 3);
    }
    {
      const unsigned short* wl = W + (size_t)li * Ee + c * 64 + g * 8;
      ushort8 w00 = *(const ushort8*)(wl);
      ushort8 w01 = *(const ushort8*)(wl + 16 * Ee);
      ushort8 w10 = *(const ushort8*)(wl + 32);
      ushort8 w11 = *(const ushort8*)(wl + 16 * Ee + 32);
      bf16x8 a0 = rd(0, 0), a1 = rd(0, 1);
      acc0 = __builtin_amdgcn_mfma_f32_16x16x32_bf16(
          a0, __builtin_bit_cast(bf16x8, w00), acc0, 0, 0, 0);
      acc1 = __builtin_amdgcn_mfma_f32_16x16x32_bf16(
          a0, __builtin_bit_cast(bf16x8, w01), acc1, 0, 0, 0);
      acc0 = __builtin_amdgcn_mfma_f32_16x16x32_bf16(
          a1, __builtin_bit_cast(bf16x8, w10), acc0, 0, 0, 0);
      acc1 = __builtin_amdgcn_mfma_f32_16x16x32_bf16(
          a1, __builtin_bit_cast(bf16x8, w11), acc1, 0, 0, 0);
    }
    wr(1, 0, B0); wr(1, 1, B1); wr(1, 2, B2); wr(1, 3, B3);
    {
      int cn = (c + 3 < 8) ? (c + 3) : 7;
      B0 = ld(cn, 0); B1 = ld(cn, 1); B2 = ld(cn, 2); B3 = ld(cn, 3);
    }
    {
      const unsigned short* wl = W + (size_t)li * Ee + (c + 1) * 64 + g * 8;
      ushort8 w00 = *(const ushort8*)(wl);
      ushort8 w01 = *(const ushort8*)(wl + 16 * Ee);
      ushort8 w10 = *(const ushort8*)(wl + 32);
      ushort8 w11 = *(const ushort8*)(wl + 16 * Ee + 32);
      bf16x8 a0 = rd(1, 0), a1 = rd(1, 1);
      acc0 = __builtin_amdgcn_mfma_f32_16x16x32_bf16(
          a0, __builtin_bit_cast(bf16x8, w00), acc0, 0, 0, 0);
      acc1 = __builtin_amdgcn_mfma_f32_16x16x32_bf16(
          a0, __builtin_bit_cast(bf16x8, w01), acc1, 0, 0, 0);
      acc0 = __builtin_amdgcn_mfma_f32_16x16x32_bf16(
          a1, __builtin_bit_cast(bf16x8, w10), acc0, 0, 0, 0);
      acc1 = __builtin_amdgcn_mfma_f32_16x16x32_bf16(
          a1, __builtin_bit_cast(bf16x8, w11), acc1, 0, 0, 0);
    }
  }

  float blo = bias[li], bhi = bias[li + 16];
  float cs = (seg == 0) ? (LOG2E / inv_scale[h]) : 1.0f;
  int sw = s0 + wv * 16;                         // wave's 16-row base (in-head)
  if (seg < 2) {
    unsigned short* ob = ((seg == 0) ? Qb : Kb) +
        (size_t)h * Ss * Dd + (size_t)(sw + 4 * g) * Dd;
    #pragma unroll
    for (int r = 0; r < 4; ++r) {
      ob[r * Dd + li]      = f2bf((acc0[r] + blo) * cs);
      ob[r * Dd + li + 16] = f2bf((acc1[r] + bhi) * cs);
    }
  } else {
    // Vt2[h][tile][d][kk]: tile = s>>5 (1024 ushorts per tile), kk = PV perm
    unsigned short* ob = Vtb + (size_t)h * Dd * Ss;
    int s0v = sw + 4 * g;
    int t = s0v >> 5;
    int kkb = 8 * g + ((s0v & 16) ? 4 : 0);      // kk base; +r, r=0..3 contiguous
    ushort4v vlo4 = { f2bf(acc0[0] + blo), f2bf(acc0[1] + blo),
                      f2bf(acc0[2] + blo), f2bf(acc0[3] + blo) };
    ushort4v vhi4 = { f2bf(acc1[0] + bhi), f2bf(acc1[1] + bhi),
                      f2bf(acc1[2] + bhi), f2bf(acc1[3] + bhi) };
    *(ushort4v*)&ob[t * 1024 + li * 32 + kkb]        = vlo4;
    *(ushort4v*)&ob[t * 1024 + (li + 16) * 32 + kkb] = vhi4;
  }
}

// ---------------- Flash attention, 4 q-tiles per wave, KV_SPLIT=8 (512-thread
// blocks). No-online-max makes partial (O,L) DIRECTLY summable across splits,
// so the combine is a plain LDS atomicAdd (ds_add_f32) into ONE shared 8 KB
// buffer — LDS drops 33->8.25 KB and waves/block double: 1024 blocks x 8
// waves = up to 32 waves/CU (was grid-capped at 16). Scalar per-tile L
// (r14-neutral) instead of ones-MFMA to cut ~12 VGPR for occupancy.
__global__ __launch_bounds__(512) void attn_kernel(
    const unsigned short* __restrict__ Qb, const unsigned short* __restrict__ Kb,
    const unsigned short* __restrict__ Vt, const unsigned int* __restrict__ mbits,
    float* __restrict__ out) {
  __shared__ float sO[4][8][64];   // [tile][r(lo0-3,hi0-3)][lane] = 8 KB
  __shared__ float sL[4][16];      // [tile][row]

  int bid  = (int)blockIdx.x;
  int slot = (bid & 7) * 128 + (bid >> 3);   // XCD-chunked, bijective (1024%8==0)
  int w    = (int)threadIdx.x >> 6;          // kv-split index 0..7
  int lane = (int)threadIdx.x & 63;
  int g = lane >> 4, li = lane & 15;
  int h = slot >> 5, qt = slot & 31;
  int q0 = qt << 6;                          // 64 q-rows per block

  // zero the shared accumulators (2048 + 64 floats, 512 threads)
  {
    float* z = &sO[0][0][0];
    int t = (int)threadIdx.x;
    z[t] = 0.f; z[t + 512] = 0.f; z[t + 1024] = 0.f; z[t + 1536] = 0.f;
    if (t < 64) (&sL[0][0])[t] = 0.f;
  }
  __syncthreads();

  const unsigned short* kb  = Kb + (size_t)h * Ss * Dd;
  const unsigned short* vpb = Vt + (size_t)h * Dd * Ss;
  const unsigned short* qrow = Qb + (size_t)h * Ss * Dd + (size_t)(q0 + li) * Dd + g * 8;
  bf16x8 qfA = __builtin_bit_cast(bf16x8, *(const ushort8*)(qrow));
  bf16x8 qfB = __builtin_bit_cast(bf16x8, *(const ushort8*)(qrow + 16 * Dd));
  bf16x8 qfC = __builtin_bit_cast(bf16x8, *(const ushort8*)(qrow + 32 * Dd));
  bf16x8 qfD = __builtin_bit_cast(bf16x8, *(const ushort8*)(qrow + 48 * Dd));
  const unsigned int* mrowA = mbits + (size_t)(q0 + li) * (Ss / 32);
  const unsigned int* mrowB = mrowA + 16 * (Ss / 32);
  const unsigned int* mrowC = mrowA + 32 * (Ss / 32);
  const unsigned int* mrowD = mrowA + 48 * (Ss / 32);
  // tile-interleaved V: lane offset within a tile (tile = 1024 ushorts)
  const unsigned short* vlo = vpb + li * 32 + 8 * g;         // d = li
  const unsigned short* vhi = vpb + (li + 16) * 32 + 8 * g;  // d = li+16

  f32x4 oloA = {0.f,0.f,0.f,0.f}, ohiA = {0.f,0.f,0.f,0.f};
  f32x4 oloB = {0.f,0.f,0.f,0.f}, ohiB = {0.f,0.f,0.f,0.f};
  f32x4 oloC = {0.f,0.f,0.f,0.f}, ohiC = {0.f,0.f,0.f,0.f};
  f32x4 oloD = {0.f,0.f,0.f,0.f}, ohiD = {0.f,0.f,0.f,0.f};
  float LA = 0.f, LB = 0.f, LC = 0.f, LD = 0.f;

  // one 32-key softmax+PV segment for one q-tile; msh = mword >> (4*g)
  auto seg = [&](f32x4 stx, f32x4 sty, unsigned int msh, float& Lp,
                 f32x4& olo, f32x4& ohi, bf16x8 vl, bf16x8 vh) {
    float p[8];
    #pragma unroll
    for (int r = 0; r < 4; ++r) {
      p[r]     = ((msh >> r) & 1u)        ? 0.f : __builtin_amdgcn_exp2f(stx[r]);
      p[4 + r] = ((msh >> (16 + r)) & 1u) ? 0.f : __builtin_amdgcn_exp2f(sty[r]);
    }
    Lp += ((p[0] + p[1]) + (p[2] + p[3])) + ((p[4] + p[5]) + (p[6] + p[7]));
    bf16x8 af;
    #pragma unroll
    for (int j = 0; j < 8; ++j) af[j] = (__bf16)p[j];
    olo = __builtin_amdgcn_mfma_f32_16x16x32_bf16(af, vl, olo, 0, 0, 0);
    ohi = __builtin_amdgcn_mfma_f32_16x16x32_bf16(af, vh, ohi, 0, 0, 0);
  };

  int g4 = 4 * g;
  int kbeg = w * KV_LEN, kend = kbeg + KV_LEN;
  for (int kt = kbeg; kt < kend; kt += 64) {
    bf16x8 k0 = __builtin_bit_cast(bf16x8, *(const ushort8*)(kb + (size_t)(kt      + li) * Dd + g * 8));
    bf16x8 k1 = __builtin_bit_cast(bf16x8, *(const ushort8*)(kb + (size_t)(kt + 16 + li) * Dd + g * 8));
    bf16x8 k2 = __builtin_bit_cast(bf16x8, *(const ushort8*)(kb + (size_t)(kt + 32 + li) * Dd + g * 8));
    bf16x8 k3 = __builtin_bit_cast(bf16x8, *(const ushort8*)(kb + (size_t)(kt + 48 + li) * Dd + g * 8));
    bf16x8 v0lo = __builtin_bit_cast(bf16x8, *(const ushort8*)(vlo + kt * 32));
    bf16x8 v0hi = __builtin_bit_cast(bf16x8, *(const ushort8*)(vhi + kt * 32));
    bf16x8 v1lo = __builtin_bit_cast(bf16x8, *(const ushort8*)(vlo + kt * 32 + 1024));
    bf16x8 v1hi = __builtin_bit_cast(bf16x8, *(const ushort8*)(vhi + kt * 32 + 1024));
    uint2 mwA = *(const uint2*)(mrowA + (kt >> 5));
    uint2 mwB = *(const uint2*)(mrowB + (kt >> 5));
    uint2 mwC = *(const uint2*)(mrowC + (kt >> 5));
    uint2 mwD = *(const uint2*)(mrowD + (kt >> 5));

    f32x4 z = {0.f, 0.f, 0.f, 0.f};
    {
      f32x4 s0 = __builtin_amdgcn_mfma_f32_16x16x32_bf16(k0, qfA, z, 0, 0, 0);
      f32x4 s1 = __builtin_amdgcn_mfma_f32_16x16x32_bf16(k1, qfA, z, 0, 0, 0);
      f32x4 s2 = __builtin_amdgcn_mfma_f32_16x16x32_bf16(k2, qfA, z, 0, 0, 0);
      f32x4 s3 = __builtin_amdgcn_mfma_f32_16x16x32_bf16(k3, qfA, z, 0, 0, 0);
      seg(s0, s1, mwA.x >> g4, LA, oloA, ohiA, v0lo, v0hi);
      seg(s2, s3, mwA.y >> g4, LA, oloA, ohiA, v1lo, v1hi);
    }
    {
      f32x4 s0 = __builtin_amdgcn_mfma_f32_16x16x32_bf16(k0, qfB, z, 0, 0, 0);
      f32x4 s1 = __builtin_amdgcn_mfma_f32_16x16x32_bf16(k1, qfB, z, 0, 0, 0);
      f32x4 s2 = __builtin_amdgcn_mfma_f32_16x16x32_bf16(k2, qfB, z, 0, 0, 0);
      f32x4 s3 = __builtin_amdgcn_mfma_f32_16x16x32_bf16(k3, qfB, z, 0, 0, 0);
      seg(s0, s1, mwB.x >> g4, LB, oloB, ohiB, v0lo, v0hi);
      seg(s2, s3, mwB.y >> g4, LB, oloB, ohiB, v1lo, v1hi);
    }
    {
      f32x4 s0 = __builtin_amdgcn_mfma_f32_16x16x32_bf16(k0, qfC, z, 0, 0, 0);
      f32x4 s1 = __builtin_amdgcn_mfma_f32_16x16x32_bf16(k1, qfC, z, 0, 0, 0);
      f32x4 s2 = __builtin_amdgcn_mfma_f32_16x16x32_bf16(k2, qfC, z, 0, 0, 0);
      f32x4 s3 = __builtin_amdgcn_mfma_f32_16x16x32_bf16(k3, qfC, z, 0, 0, 0);
      seg(s0, s1, mwC.x >> g4, LC, oloC, ohiC, v0lo, v0hi);
      seg(s2, s3, mwC.y >> g4, LC, oloC, ohiC, v1lo, v1hi);
    }
    {
      f32x4 s0 = __builtin_amdgcn_mfma_f32_16x16x32_bf16(k0, qfD, z, 0, 0, 0);
      f32x4 s1 = __builtin_amdgcn_mfma_f32_16x16x32_bf16(k1, qfD, z, 0, 0, 0);
      f32x4 s2 = __builtin_amdgcn_mfma_f32_16x16x32_bf16(k2, qfD, z, 0, 0, 0);
      f32x4 s3 = __builtin_amdgcn_mfma_f32_16x16x32_bf16(k3, qfD, z, 0, 0, 0);
      seg(s0, s1, mwD.x >> g4, LD, oloD, ohiD, v0lo, v0hi);
      seg(s2, s3, mwD.y >> g4, LD, oloD, ohiD, v1lo, v1hi);
    }
  }

  // reduce L over the 4 g-replicas (lane then holds row li's full sum
  // for this wave's key range)
  LA += __shfl_xor(LA, 16); LA += __shfl_xor(LA, 32);
  LB += __shfl_xor(LB, 16); LB += __shfl_xor(LB, 32);
  LC += __shfl_xor(LC, 16); LC += __shfl_xor(LC, 32);
  LD += __shfl_xor(LD, 16); LD += __shfl_xor(LD, 32);

  // accumulate partials into the shared buffer (no-online-max => plain sums)
  #pragma unroll
  for (int r = 0; r < 4; ++r) {
    atomicAdd(&sO[0][r][lane],     oloA[r]);
    atomicAdd(&sO[0][4 + r][lane], ohiA[r]);
    atomicAdd(&sO[1][r][lane],     oloB[r]);
    atomicAdd(&sO[1][4 + r][lane], ohiB[r]);
    atomicAdd(&sO[2][r][lane],     oloC[r]);
    atomicAdd(&sO[2][4 + r][lane], ohiC[r]);
    atomicAdd(&sO[3][r][lane],     oloD[r]);
    atomicAdd(&sO[3][4 + r][lane], ohiD[r]);
  }
  if (lane < 16) {
    atomicAdd(&sL[0][li], LA);
    atomicAdd(&sL[1][li], LB);
    atomicAdd(&sL[2][li], LC);
    atomicAdd(&sL[3][li], LD);
  }
  __syncthreads();

  if (w < 4) {   // wave w finalizes tile w (16 rows x 32 cols)
    float* ob = out + (size_t)h * Ss * Dd + (size_t)(q0 + w * 16) * Dd;
    #pragma unroll
    for (int r = 0; r < 4; ++r) {
      int row = 4 * g + r;
      float inv = 1.0f / sL[w][row];
      ob[row * Dd + li]      = sO[w][r][lane] * inv;
      ob[row * Dd + li + 16] = sO[w][4 + r][lane] * inv;
    }
  }
}

extern "C" void kernel_launch(void* const* d_in, const int* in_sizes, int n_in,
                              void* d_out, int out_size, void* d_ws, size_t ws_size,
                              hipStream_t stream) {
  const float* query = (const float*)d_in[0];
  const float* key   = (const float*)d_in[1];
  const float* value = (const float*)d_in[2];
  const int*   mask  = (const int*)d_in[3];
  const float* Wq = (const float*)d_in[4];
  const float* bq = (const float*)d_in[5];
  const float* Wk = (const float*)d_in[6];
  const float* bk = (const float*)d_in[7];
  const float* Wv = (const float*)d_in[8];
  const float* bv = (const float*)d_in[9];
  const float* inv_scale = (const float*)d_in[10];

  unsigned short* Qb   = (unsigned short*)d_ws;
  unsigned short* Kbuf = Qb + (size_t)Hh * Ss * Dd;
  unsigned short* Vtb  = Kbuf + (size_t)Hh * Ss * Dd;
  unsigned int*   bits = (unsigned int*)(Vtb + (size_t)Hh * Dd * Ss);
  unsigned short* Wb   = (unsigned short*)(bits + (size_t)Ss * Ss / 32);
  float* out = (float*)d_out;

  prep_kernel<<<512 + 48, dim3(256), 0, stream>>>(mask, bits, Wq, Wk, Wv, Wb);
  proj_kernel<<<3072, dim3(256), 0, stream>>>(query, key, value, Wb, bq, bk, bv,
                                              inv_scale, Qb, Kbuf, Vtb);
  attn_kernel<<<1024, dim3(512), 0, stream>>>(Qb, Kbuf, Vtb, bits, out);
}

// Round 18
// 137.259 us; speedup vs baseline: 1.6223x; 1.6223x over previous
//
#include <hip/hip_runtime.h>

#define Hh 32
#define Ss 2048
#define Ee 512
#define Dd 32
#define LOG2E 1.4426950408889634f
#define KV_SPLIT 4
#define KV_LEN (Ss / KV_SPLIT)   // 512 keys per wave

typedef __attribute__((ext_vector_type(4))) float f32x4;
typedef __attribute__((ext_vector_type(4))) int i32x4;
typedef __attribute__((ext_vector_type(8))) __bf16 bf16x8;
typedef __attribute__((ext_vector_type(8))) unsigned short ushort8;
typedef __attribute__((ext_vector_type(4))) unsigned short ushort4v;

// float -> bf16 round-to-nearest-even, as raw ushort
__device__ inline unsigned short f2bf(float f) {
  union { float f; unsigned u; } x; x.f = f;
  unsigned r = x.u + 0x7fffu + ((x.u >> 16) & 1u);
  return (unsigned short)(r >> 16);
}

// ---------------- Prep: pack mask int32 -> bits, convert Wq|Wk|Wv -> bf16
__global__ __launch_bounds__(256) void prep_kernel(
    const int* __restrict__ mask, unsigned int* __restrict__ bits,
    const float* __restrict__ Wq, const float* __restrict__ Wk,
    const float* __restrict__ Wv, unsigned short* __restrict__ Wb) {
  int b = (int)blockIdx.x, t = (int)threadIdx.x;
  if (b < 512) {
    int w = b * 256 + t;  // word index 0..S*S/32-1
    const i32x4* p = (const i32x4*)(mask + (size_t)w * 32);
    unsigned int bs = 0;
    #pragma unroll
    for (int i = 0; i < 8; ++i) {
      i32x4 v = __builtin_nontemporal_load(&p[i]);   // stream-once: bypass L3
      bs |= (v.x ? 1u : 0u) << (4 * i + 0);
      bs |= (v.y ? 1u : 0u) << (4 * i + 1);
      bs |= (v.z ? 1u : 0u) << (4 * i + 2);
      bs |= (v.w ? 1u : 0u) << (4 * i + 3);
    }
    bits[w] = bs;
  } else {
    int i = (b - 512) * 1024 + t * 4;  // 48 blocks cover 3*32*512 = 49152 elems
    const float* src = (i < 16384) ? (Wq + i)
                     : (i < 32768) ? (Wk + (i - 16384)) : (Wv + (i - 32768));
    f32x4 v = *(const f32x4*)src;
    ushort4v o = { f2bf(v.x), f2bf(v.y), f2bf(v.z), f2bf(v.w) };
    *(ushort4v*)(Wb + i) = o;
  }
}

// ---------------- Merged projections, BARRIER-FREE per-wave pipeline with
// NONTEMPORAL input loads (confirmed: proj 130 -> ~84 us; ~1.35x of the
// mixed-L3/HBM streaming floor, warm replays equally fast -> low leverage).
// V written in TILE-INTERLEAVED layout Vt2[h][s/32][d][kk].
__global__ __launch_bounds__(256) void proj_kernel(
    const float* __restrict__ Xq, const float* __restrict__ Xk,
    const float* __restrict__ Xv, const unsigned short* __restrict__ Wb,
    const float* __restrict__ bq, const float* __restrict__ bk,
    const float* __restrict__ bv, const float* __restrict__ inv_scale,
    unsigned short* __restrict__ Qb, unsigned short* __restrict__ Kb,
    unsigned short* __restrict__ Vtb) {
  __shared__ unsigned short sb[4][2][16 * 64];   // [wave][buf][16 rows x 64 bf16]

  int blk  = (int)blockIdx.x;
  int seg  = blk >> 10;
  int tid  = (int)threadIdx.x;
  int wv   = tid >> 6, lane = tid & 63;
  int g = lane >> 4, li = lane & 15;
  int lr = lane >> 4;      // row-within-quad for loads (0..3)
  int lc = lane & 15;      // col group (4 floats = 16 B)
  int R0 = (blk & 1023) * 64;        // block row base within segment
  int h  = R0 >> 11;
  int s0 = R0 & 2047;

  const float* X    = (seg == 0) ? Xq : (seg == 1) ? Xk : Xv;
  const float* bias = (seg == 0) ? bq : (seg == 1) ? bk : bv;
  const unsigned short* W = Wb + seg * (Dd * Ee);
  const float* xw = X + (size_t)(R0 + wv * 16) * Ee;   // wave's 16 rows

  unsigned short (*mybuf)[16 * 64] = sb[wv];

  auto ld = [&](int c, int i) -> f32x4 {
    return __builtin_nontemporal_load(
        (const f32x4*)(xw + (size_t)(4 * i + lr) * Ee + c * 64 + lc * 4));
  };
  auto wr = [&](int buf, int i, f32x4 v) {
    int r = 4 * i + lr;
    int byteoff = (lc * 8) ^ ((r & 7) << 4);
    ushort4v u = { f2bf(v.x), f2bf(v.y), f2bf(v.z), f2bf(v.w) };
    *(ushort4v*)&mybuf[buf][r * 64 + (byteoff >> 1)] = u;
  };
  auto rd = [&](int buf, int half) -> bf16x8 {
    int byteoff = (half * 64 + g * 16) ^ ((li & 7) << 4);
    return __builtin_bit_cast(bf16x8,
        *(const ushort8*)&mybuf[buf][li * 64 + (byteoff >> 1)]);
  };

  f32x4 acc0 = {0.f, 0.f, 0.f, 0.f};
  f32x4 acc1 = {0.f, 0.f, 0.f, 0.f};

  f32x4 A0 = ld(0, 0), A1 = ld(0, 1), A2 = ld(0, 2), A3 = ld(0, 3);
  f32x4 B0 = ld(1, 0), B1 = ld(1, 1), B2 = ld(1, 2), B3 = ld(1, 3);

  #pragma unroll
  for (int c = 0; c < 8; c += 2) {
    wr(0, 0, A0); wr(0, 1, A1); wr(0, 2, A2); wr(0, 3, A3);
    {
      int cn = (c + 2 < 8) ? (c + 2) : 6;   // clamped redundant reload
      A0 = ld(cn, 0); A1 = ld(cn, 1); A2 = ld(cn, 2); A3 = ld(cn, 3);
    }
    {
      const unsigned short* wl = W + (size_t)li * Ee + c * 64 + g * 8;
      ushort8 w00 = *(const ushort8*)(wl);
      ushort8 w01 = *(const ushort8*)(wl + 16 * Ee);
      ushort8 w10 = *(const ushort8*)(wl + 32);
      ushort8 w11 = *(const ushort8*)(wl + 16 * Ee + 32);
      bf16x8 a0 = rd(0, 0), a1 = rd(0, 1);
      acc0 = __builtin_amdgcn_mfma_f32_16x16x32_bf16(
          a0, __builtin_bit_cast(bf16x8, w00), acc0, 0, 0, 0);
      acc1 = __builtin_amdgcn_mfma_f32_16x16x32_bf16(
          a0, __builtin_bit_cast(bf16x8, w01), acc1, 0, 0, 0);
      acc0 = __builtin_amdgcn_mfma_f32_16x16x32_bf16(
          a1, __builtin_bit_cast(bf16x8, w10), acc0, 0, 0, 0);
      acc1 = __builtin_amdgcn_mfma_f32_16x16x32_bf16(
          a1, __builtin_bit_cast(bf16x8, w11), acc1, 0, 0, 0);
    }
    wr(1, 0, B0); wr(1, 1, B1); wr(1, 2, B2); wr(1, 3, B3);
    {
      int cn = (c + 3 < 8) ? (c + 3) : 7;
      B0 = ld(cn, 0); B1 = ld(cn, 1); B2 = ld(cn, 2); B3 = ld(cn, 3);
    }
    {
      const unsigned short* wl = W + (size_t)li * Ee + (c + 1) * 64 + g * 8;
      ushort8 w00 = *(const ushort8*)(wl);
      ushort8 w01 = *(const ushort8*)(wl + 16 * Ee);
      ushort8 w10 = *(const ushort8*)(wl + 32);
      ushort8 w11 = *(const ushort8*)(wl + 16 * Ee + 32);
      bf16x8 a0 = rd(1, 0), a1 = rd(1, 1);
      acc0 = __builtin_amdgcn_mfma_f32_16x16x32_bf16(
          a0, __builtin_bit_cast(bf16x8, w00), acc0, 0, 0, 0);
      acc1 = __builtin_amdgcn_mfma_f32_16x16x32_bf16(
          a0, __builtin_bit_cast(bf16x8, w01), acc1, 0, 0, 0);
      acc0 = __builtin_amdgcn_mfma_f32_16x16x32_bf16(
          a1, __builtin_bit_cast(bf16x8, w10), acc0, 0, 0, 0);
      acc1 = __builtin_amdgcn_mfma_f32_16x16x32_bf16(
          a1, __builtin_bit_cast(bf16x8, w11), acc1, 0, 0, 0);
    }
  }

  float blo = bias[li], bhi = bias[li + 16];
  float cs = (seg == 0) ? (LOG2E / inv_scale[h]) : 1.0f;
  int sw = s0 + wv * 16;                         // wave's 16-row base (in-head)
  if (seg < 2) {
    unsigned short* ob = ((seg == 0) ? Qb : Kb) +
        (size_t)h * Ss * Dd + (size_t)(sw + 4 * g) * Dd;
    #pragma unroll
    for (int r = 0; r < 4; ++r) {
      ob[r * Dd + li]      = f2bf((acc0[r] + blo) * cs);
      ob[r * Dd + li + 16] = f2bf((acc1[r] + bhi) * cs);
    }
  } else {
    // Vt2[h][tile][d][kk]: tile = s>>5 (1024 ushorts per tile), kk = PV perm
    unsigned short* ob = Vtb + (size_t)h * Dd * Ss;
    int s0v = sw + 4 * g;
    int t = s0v >> 5;
    int kkb = 8 * g + ((s0v & 16) ? 4 : 0);      // kk base; +r, r=0..3 contiguous
    ushort4v vlo4 = { f2bf(acc0[0] + blo), f2bf(acc0[1] + blo),
                      f2bf(acc0[2] + blo), f2bf(acc0[3] + blo) };
    ushort4v vhi4 = { f2bf(acc1[0] + bhi), f2bf(acc1[1] + bhi),
                      f2bf(acc1[2] + bhi), f2bf(acc1[3] + bhi) };
    *(ushort4v*)&ob[t * 1024 + li * 32 + kkb]        = vlo4;
    *(ushort4v*)&ob[t * 1024 + (li + 16) * 32 + kkb] = vhi4;
  }
}

// ---------------- Flash attention, 4 q-tiles per wave, no online max.
// (Round-16 version, reverted from the KV_SPLIT=8 experiment which dropped
// occupancy to 23% — 512-thread blocks are a coarse co-residency quantum.)
// V read from tile-interleaved Vt2[h][tile][d][kk]: each V-frag load is one
// contiguous 1 KB block per wave instruction, same coalescing as K.
__global__ __launch_bounds__(256) void attn_kernel(
    const unsigned short* __restrict__ Qb, const unsigned short* __restrict__ Kb,
    const unsigned short* __restrict__ Vt, const unsigned int* __restrict__ mbits,
    float* __restrict__ out) {
  __shared__ float sO[KV_SPLIT][4][8][64];
  __shared__ float sL[KV_SPLIT][4][16];

  int bid  = (int)blockIdx.x;
  int slot = (bid & 7) * 128 + (bid >> 3);   // XCD-chunked, bijective (1024%8==0)
  int w    = (int)threadIdx.x >> 6;          // kv-split index 0..3
  int lane = (int)threadIdx.x & 63;
  int g = lane >> 4, li = lane & 15;
  int h = slot >> 5, qt = slot & 31;
  int q0 = qt << 6;                          // 64 q-rows per block

  const unsigned short* kb  = Kb + (size_t)h * Ss * Dd;
  const unsigned short* vpb = Vt + (size_t)h * Dd * Ss;
  const unsigned short* qrow = Qb + (size_t)h * Ss * Dd + (size_t)(q0 + li) * Dd + g * 8;
  bf16x8 qfA = __builtin_bit_cast(bf16x8, *(const ushort8*)(qrow));
  bf16x8 qfB = __builtin_bit_cast(bf16x8, *(const ushort8*)(qrow + 16 * Dd));
  bf16x8 qfC = __builtin_bit_cast(bf16x8, *(const ushort8*)(qrow + 32 * Dd));
  bf16x8 qfD = __builtin_bit_cast(bf16x8, *(const ushort8*)(qrow + 48 * Dd));
  const unsigned int* mrowA = mbits + (size_t)(q0 + li) * (Ss / 32);
  const unsigned int* mrowB = mrowA + 16 * (Ss / 32);
  const unsigned int* mrowC = mrowA + 32 * (Ss / 32);
  const unsigned int* mrowD = mrowA + 48 * (Ss / 32);
  // tile-interleaved V: lane offset within a tile (tile = 1024 ushorts)
  const unsigned short* vlo = vpb + li * 32 + 8 * g;         // d = li
  const unsigned short* vhi = vpb + (li + 16) * 32 + 8 * g;  // d = li+16

  ushort8 onesu = { 0x3F80, 0x3F80, 0x3F80, 0x3F80,
                    0x3F80, 0x3F80, 0x3F80, 0x3F80 };     // bf16 1.0 x8
  bf16x8 ones = __builtin_bit_cast(bf16x8, onesu);

  f32x4 oloA = {0.f,0.f,0.f,0.f}, ohiA = {0.f,0.f,0.f,0.f}, lA = {0.f,0.f,0.f,0.f};
  f32x4 oloB = {0.f,0.f,0.f,0.f}, ohiB = {0.f,0.f,0.f,0.f}, lB = {0.f,0.f,0.f,0.f};
  f32x4 oloC = {0.f,0.f,0.f,0.f}, ohiC = {0.f,0.f,0.f,0.f}, lC = {0.f,0.f,0.f,0.f};
  f32x4 oloD = {0.f,0.f,0.f,0.f}, ohiD = {0.f,0.f,0.f,0.f}, lD = {0.f,0.f,0.f,0.f};

  // one 32-key softmax+PV segment for one q-tile; msh = mword >> (4*g)
  auto seg = [&](f32x4 stx, f32x4 sty, unsigned int msh,
                 f32x4& lacc, f32x4& olo, f32x4& ohi, bf16x8 vl, bf16x8 vh) {
    float p[8];
    #pragma unroll
    for (int r = 0; r < 4; ++r) {
      p[r]     = ((msh >> r) & 1u)        ? 0.f : __builtin_amdgcn_exp2f(stx[r]);
      p[4 + r] = ((msh >> (16 + r)) & 1u) ? 0.f : __builtin_amdgcn_exp2f(sty[r]);
    }
    bf16x8 af;
    #pragma unroll
    for (int j = 0; j < 8; ++j) af[j] = (__bf16)p[j];
    olo  = __builtin_amdgcn_mfma_f32_16x16x32_bf16(af, vl, olo, 0, 0, 0);
    ohi  = __builtin_amdgcn_mfma_f32_16x16x32_bf16(af, vh, ohi, 0, 0, 0);
    lacc = __builtin_amdgcn_mfma_f32_16x16x32_bf16(af, ones, lacc, 0, 0, 0);
  };

  int g4 = 4 * g;
  int kbeg = w * KV_LEN, kend = kbeg + KV_LEN;
  for (int kt = kbeg; kt < kend; kt += 64) {
    bf16x8 k0 = __builtin_bit_cast(bf16x8, *(const ushort8*)(kb + (size_t)(kt      + li) * Dd + g * 8));
    bf16x8 k1 = __builtin_bit_cast(bf16x8, *(const ushort8*)(kb + (size_t)(kt + 16 + li) * Dd + g * 8));
    bf16x8 k2 = __builtin_bit_cast(bf16x8, *(const ushort8*)(kb + (size_t)(kt + 32 + li) * Dd + g * 8));
    bf16x8 k3 = __builtin_bit_cast(bf16x8, *(const ushort8*)(kb + (size_t)(kt + 48 + li) * Dd + g * 8));
    // V frags: tile kt>>5 at byte-contiguous vlo/vhi (+1024 for next tile)
    bf16x8 v0lo = __builtin_bit_cast(bf16x8, *(const ushort8*)(vlo + kt * 32));
    bf16x8 v0hi = __builtin_bit_cast(bf16x8, *(const ushort8*)(vhi + kt * 32));
    bf16x8 v1lo = __builtin_bit_cast(bf16x8, *(const ushort8*)(vlo + kt * 32 + 1024));
    bf16x8 v1hi = __builtin_bit_cast(bf16x8, *(const ushort8*)(vhi + kt * 32 + 1024));
    uint2 mwA = *(const uint2*)(mrowA + (kt >> 5));
    uint2 mwB = *(const uint2*)(mrowB + (kt >> 5));
    uint2 mwC = *(const uint2*)(mrowC + (kt >> 5));
    uint2 mwD = *(const uint2*)(mrowD + (kt >> 5));

    f32x4 z = {0.f, 0.f, 0.f, 0.f};
    {
      f32x4 s0 = __builtin_amdgcn_mfma_f32_16x16x32_bf16(k0, qfA, z, 0, 0, 0);
      f32x4 s1 = __builtin_amdgcn_mfma_f32_16x16x32_bf16(k1, qfA, z, 0, 0, 0);
      f32x4 s2 = __builtin_amdgcn_mfma_f32_16x16x32_bf16(k2, qfA, z, 0, 0, 0);
      f32x4 s3 = __builtin_amdgcn_mfma_f32_16x16x32_bf16(k3, qfA, z, 0, 0, 0);
      seg(s0, s1, mwA.x >> g4, lA, oloA, ohiA, v0lo, v0hi);
      seg(s2, s3, mwA.y >> g4, lA, oloA, ohiA, v1lo, v1hi);
    }
    {
      f32x4 s0 = __builtin_amdgcn_mfma_f32_16x16x32_bf16(k0, qfB, z, 0, 0, 0);
      f32x4 s1 = __builtin_amdgcn_mfma_f32_16x16x32_bf16(k1, qfB, z, 0, 0, 0);
      f32x4 s2 = __builtin_amdgcn_mfma_f32_16x16x32_bf16(k2, qfB, z, 0, 0, 0);
      f32x4 s3 = __builtin_amdgcn_mfma_f32_16x16x32_bf16(k3, qfB, z, 0, 0, 0);
      seg(s0, s1, mwB.x >> g4, lB, oloB, ohiB, v0lo, v0hi);
      seg(s2, s3, mwB.y >> g4, lB, oloB, ohiB, v1lo, v1hi);
    }
    {
      f32x4 s0 = __builtin_amdgcn_mfma_f32_16x16x32_bf16(k0, qfC, z, 0, 0, 0);
      f32x4 s1 = __builtin_amdgcn_mfma_f32_16x16x32_bf16(k1, qfC, z, 0, 0, 0);
      f32x4 s2 = __builtin_amdgcn_mfma_f32_16x16x32_bf16(k2, qfC, z, 0, 0, 0);
      f32x4 s3 = __builtin_amdgcn_mfma_f32_16x16x32_bf16(k3, qfC, z, 0, 0, 0);
      seg(s0, s1, mwC.x >> g4, lC, oloC, ohiC, v0lo, v0hi);
      seg(s2, s3, mwC.y >> g4, lC, oloC, ohiC, v1lo, v1hi);
    }
    {
      f32x4 s0 = __builtin_amdgcn_mfma_f32_16x16x32_bf16(k0, qfD, z, 0, 0, 0);
      f32x4 s1 = __builtin_amdgcn_mfma_f32_16x16x32_bf16(k1, qfD, z, 0, 0, 0);
      f32x4 s2 = __builtin_amdgcn_mfma_f32_16x16x32_bf16(k2, qfD, z, 0, 0, 0);
      f32x4 s3 = __builtin_amdgcn_mfma_f32_16x16x32_bf16(k3, qfD, z, 0, 0, 0);
      seg(s0, s1, mwD.x >> g4, lD, oloD, ohiD, v0lo, v0hi);
      seg(s2, s3, mwD.y >> g4, lD, oloD, ohiD, v1lo, v1hi);
    }
  }

  // lacc[r] is the full row-sum for q-row 4g+r, replicated across li
  if (li == 0) {
    #pragma unroll
    for (int r = 0; r < 4; ++r) {
      sL[w][0][4 * g + r] = lA[r];
      sL[w][1][4 * g + r] = lB[r];
      sL[w][2][4 * g + r] = lC[r];
      sL[w][3][4 * g + r] = lD[r];
    }
  }
  #pragma unroll
  for (int r = 0; r < 4; ++r) {
    sO[w][0][r][lane]     = oloA[r];
    sO[w][0][4 + r][lane] = ohiA[r];
    sO[w][1][r][lane]     = oloB[r];
    sO[w][1][4 + r][lane] = ohiB[r];
    sO[w][2][r][lane]     = oloC[r];
    sO[w][2][4 + r][lane] = ohiC[r];
    sO[w][3][r][lane]     = oloD[r];
    sO[w][3][4 + r][lane] = ohiD[r];
  }
  __syncthreads();

  {
    int hf = w;   // each wave finalizes one 16-row group
    float* ob = out + (size_t)h * Ss * Dd + (size_t)(q0 + hf * 16) * Dd;
    #pragma unroll
    for (int r = 0; r < 4; ++r) {
      int row = 4 * g + r;
      float den = sL[0][hf][row] + sL[1][hf][row] +
                  sL[2][hf][row] + sL[3][hf][row];
      float nlo = sO[0][hf][r][lane] + sO[1][hf][r][lane] +
                  sO[2][hf][r][lane] + sO[3][hf][r][lane];
      float nhi = sO[0][hf][4 + r][lane] + sO[1][hf][4 + r][lane] +
                  sO[2][hf][4 + r][lane] + sO[3][hf][4 + r][lane];
      float inv = 1.0f / den;
      ob[row * Dd + li]      = nlo * inv;
      ob[row * Dd + li + 16] = nhi * inv;
    }
  }
}

extern "C" void kernel_launch(void* const* d_in, const int* in_sizes, int n_in,
                              void* d_out, int out_size, void* d_ws, size_t ws_size,
                              hipStream_t stream) {
  const float* query = (const float*)d_in[0];
  const float* key   = (const float*)d_in[1];
  const float* value = (const float*)d_in[2];
  const int*   mask  = (const int*)d_in[3];
  const float* Wq = (const float*)d_in[4];
  const float* bq = (const float*)d_in[5];
  const float* Wk = (const float*)d_in[6];
  const float* bk = (const float*)d_in[7];
  const float* Wv = (const float*)d_in[8];
  const float* bv = (const float*)d_in[9];
  const float* inv_scale = (const float*)d_in[10];

  unsigned short* Qb   = (unsigned short*)d_ws;
  unsigned short* Kbuf = Qb + (size_t)Hh * Ss * Dd;
  unsigned short* Vtb  = Kbuf + (size_t)Hh * Ss * Dd;
  unsigned int*   bits = (unsigned int*)(Vtb + (size_t)Hh * Dd * Ss);
  unsigned short* Wb   = (unsigned short*)(bits + (size_t)Ss * Ss / 32);
  float* out = (float*)d_out;

  prep_kernel<<<512 + 48, dim3(256), 0, stream>>>(mask, bits, Wq, Wk, Wv, Wb);
  proj_kernel<<<3072, dim3(256), 0, stream>>>(query, key, value, Wb, bq, bk, bv,
                                              inv_scale, Qb, Kbuf, Vtb);
  attn_kernel<<<1024, dim3(256), 0, stream>>>(Qb, Kbuf, Vtb, bits, out);
}